// Round 2
// baseline (2321.709 us; speedup 1.0000x reference)
//
#include <hip/hip_runtime.h>
#include <math.h>

// B=4096 images, P=4096 pixels, F=1024 filters, 50 AdamW steps.
// Round 7: pin VGPR budget. Round-6 evidence: VGPR_Count=64 (allocator
// defaulted to 8 waves/EU target) with ~110-reg working set -> 2.48 GB
// scratch traffic, dur == traffic/1.19TB/s. LDS=96KB already hard-limits
// occupancy to 1 block/CU = 4 waves/EU, so a 128-reg budget costs nothing:
// amdgpu_waves_per_eu(4,4) pins it. Math unchanged -> bit-identical outputs.

typedef __bf16 bf16_t;
typedef __bf16 bf16x8 __attribute__((ext_vector_type(8)));
typedef __bf16 bf16x4 __attribute__((ext_vector_type(4)));
typedef float f32x4 __attribute__((ext_vector_type(4)));

__device__ __forceinline__ void async_ld16(const void* g, void* l) {
    __builtin_amdgcn_global_load_lds(
        (const __attribute__((address_space(1))) void*)g,
        (__attribute__((address_space(3))) void*)l, 16, 0, 0);
}

__global__ void cvt_bf16(const float* __restrict__ x, bf16_t* __restrict__ y, long n) {
    long i = ((long)blockIdx.x * blockDim.x + threadIdx.x) * 4;
    if (i + 3 < n) {
        float4 f = *(const float4*)(x + i);
        bf16x4 o = { (bf16_t)f.x, (bf16_t)f.y, (bf16_t)f.z, (bf16_t)f.w };
        *(bf16x4*)(y + i) = o;
    }
}

// PhiT[f][p] = Phi[p][f], fp32 -> bf16.  Phi is [4096,1024].
__global__ void transpose_cvt(const float* __restrict__ src, bf16_t* __restrict__ dst) {
    __shared__ float tile[32][33];
    const int f0 = blockIdx.x * 32;
    const int p0 = blockIdx.y * 32;
    const int tx = threadIdx.x, ty = threadIdx.y;
    for (int r = ty; r < 32; r += 8)
        tile[r][tx] = src[(size_t)(p0 + r) * 1024 + f0 + tx];
    __syncthreads();
    for (int r = ty; r < 32; r += 8)
        dst[(size_t)(f0 + r) * 4096 + p0 + tx] = (bf16_t)tile[tx][r];
}

// C[M,N] = A[M,K] @ BT[N,K]^T (bf16, K-major). 128x128 tile, BK=32.
// MODE 0: store C fp32.  MODE 3: store C bf16 in blocked layout
//   Gblk[row/32][col][row%32]  (requires N==1024).
template<int MODE>
__global__ __launch_bounds__(256) void gemm_bt(
    const bf16_t* __restrict__ A, const bf16_t* __restrict__ BT,
    int M, int N, int K,
    float* __restrict__ Cf, bf16_t* __restrict__ Cb)
{
    __shared__ bf16_t As[128 * 32];
    __shared__ bf16_t Bs[128 * 32];
    const int tid  = threadIdx.x;
    const int n0   = blockIdx.x * 128;
    const int m0   = blockIdx.y * 128;
    const int wave = tid >> 6;
    const int lane = tid & 63;
    const int wm   = (wave >> 1) * 64;
    const int wn   = (wave & 1) * 64;
    const int r0   = tid >> 2;
    const int kc   = (tid & 3) * 8;
    const int lr   = lane >> 4;
    const int lc   = lane & 15;

    f32x4 acc[4][4] = {};
    const size_t arow0 = (size_t)(m0 + r0) * K;
    const size_t arow1 = (size_t)(m0 + 64 + r0) * K;
    const size_t brow0 = (size_t)(n0 + r0) * K;
    const size_t brow1 = (size_t)(n0 + 64 + r0) * K;

    for (int k0 = 0; k0 < K; k0 += 32) {
        async_ld16(A + arow0 + k0 + kc, &As[(size_t)tid * 8]);
        async_ld16(A + arow1 + k0 + kc, &As[(size_t)(tid + 256) * 8]);
        async_ld16(BT + brow0 + k0 + kc, &Bs[(size_t)tid * 8]);
        async_ld16(BT + brow1 + k0 + kc, &Bs[(size_t)(tid + 256) * 8]);
        __syncthreads();
        bf16x8 af[4], bv[4];
#pragma unroll
        for (int i = 0; i < 4; ++i) {
            af[i] = *(const bf16x8*)&As[(wm + i * 16 + lc) * 32 + lr * 8];
            bv[i] = *(const bf16x8*)&Bs[(wn + i * 16 + lc) * 32 + lr * 8];
        }
#pragma unroll
        for (int i = 0; i < 4; ++i)
#pragma unroll
            for (int j = 0; j < 4; ++j)
                acc[i][j] = __builtin_amdgcn_mfma_f32_16x16x32_bf16(af[i], bv[j], acc[i][j], 0, 0, 0);
        __syncthreads();
    }

    // C/D layout: col = lane&15, row = (lane>>4)*4 + reg
#pragma unroll
    for (int i = 0; i < 4; ++i)
#pragma unroll
        for (int t = 0; t < 4; ++t) {
            const int row = m0 + wm + i * 16 + lr * 4 + t;
#pragma unroll
            for (int j = 0; j < 4; ++j) {
                const int col = n0 + wn + j * 16 + lc;
                if constexpr (MODE == 0) {
                    Cf[(size_t)row * N + col] = acc[i][j][t];
                } else {
                    Cb[(size_t)(((row >> 5) << 10) + col) * 32 + (row & 31)] =
                        (bf16_t)acc[i][j][t];
                }
            }
        }
}

// Persistent LCA: each block owns 16 rows for all 50 steps.
// 1024 threads = 16 waves; wave w covers cols [w*64, w*64+64) (4 n-tiles).
// State u,m,v in registers (48 VGPRs); excite in LDS fp32 (64 KB);
// act bf16 in LDS (32 KB, 16B units swizzled: unit ^= (row&7));
// G read from L2 via blocked layout Gblk[k/32][n][k%32] (coalesced 1KB/wave-inst).
// LDS=96KB -> 1 block/CU = exactly 4 waves/EU; amdgpu_waves_per_eu(4,4) pins
// the allocator to the matching 128-VGPR budget (default 8/EU target chose 64
// and spilled 2.4 GB of scratch traffic in round 6).
__global__ __launch_bounds__(1024) __attribute__((amdgpu_waves_per_eu(4, 4)))
void lca_persistent(
    const bf16_t* __restrict__ Gblk, const float* __restrict__ excite,
    float* __restrict__ actsf, bf16_t* __restrict__ actbf)
{
    __shared__ bf16_t act[16 * 1024];   // 32 KB, swizzled
    __shared__ float  exs[16 * 1024];   // 64 KB, exs[row][col] == global layout
    const int tid  = threadIdx.x;
    const int m0   = blockIdx.x * 16;
    const int wave = tid >> 6;
    const int lane = tid & 63;
    const int lr   = lane >> 4;
    const int lc   = lane & 15;
    const int wn   = wave * 64;

    // zero act buffer (act_1 = relu(0 - 0.25) = 0)
    for (int i = tid; i < 16 * 1024 / 8; i += 1024) {
        bf16x8 z = {};
        *(bf16x8*)&act[i * 8] = z;
    }
    // stage excite rows [m0, m0+16) into LDS (contiguous copy, 16B/lane)
    {
        const float* esrc = excite + (size_t)m0 * 1024;
        for (int i = tid; i < 16 * 1024 / 4; i += 1024)
            *(f32x4*)&exs[i * 4] = *(const f32x4*)(esrc + (size_t)i * 4);
    }
    __syncthreads();

    f32x4 U[4] = {}, Mo[4] = {}, Vo[4] = {};

    // per-thread invariant offsets
    const int aoff = lc * 1024;       // act row base (elements)
    const int lcx  = lc & 7;
    int goff[4];
#pragma unroll
    for (int j = 0; j < 4; ++j)
        goff[j] = ((wn + j * 16 + lc) << 5) + lr * 8;

    const float lrate = 0.1f, b1 = 0.9f, b2 = 0.999f, eps = 1e-8f;
    const float wdmul = 1.0f - lrate * 1e-2f;
    float pb1 = 1.0f, pb2 = 1.0f;

    for (int step = 1; step <= 50; ++step) {
        pb1 *= b1; pb2 *= b2;
        const float inv1 = 1.0f / (1.0f - pb1);
        const float inv2 = 1.0f / (1.0f - pb2);

        f32x4 acc[4] = {};
#pragma unroll 2
        for (int kcb = 0; kcb < 32; ++kcb) {
            // A-fragment: act[m = lc][k = kcb*32 + lr*8 + 0..7], swizzled
            const int unit = kcb * 4 + lr;
            const bf16x8 a = *(const bf16x8*)&act[aoff + (((unit ^ lcx)) << 3)];
            const bf16_t* gp = Gblk + ((size_t)kcb << 15);
            bf16x8 b[4];
#pragma unroll
            for (int j = 0; j < 4; ++j)
                b[j] = *(const bf16x8*)(gp + goff[j]);
#pragma unroll
            for (int j = 0; j < 4; ++j)
                acc[j] = __builtin_amdgcn_mfma_f32_16x16x32_bf16(a, b[j], acc[j], 0, 0, 0);
        }
        __syncthreads();   // all waves done reading act

#pragma unroll
        for (int j = 0; j < 4; ++j)
#pragma unroll
            for (int t = 0; t < 4; ++t) {
                const int row = lr * 4 + t;
                const int col = wn + j * 16 + lc;
                const float ex   = exs[row * 1024 + col];
                const float uold = U[j][t];
                const float aold = fmaxf(uold - 0.25f, 0.0f);
                const float g    = uold - ex + acc[j][t] - aold;
                const float mn   = b1 * Mo[j][t] + (1.0f - b1) * g;
                const float vn   = b2 * Vo[j][t] + (1.0f - b2) * g * g;
                float un = uold * wdmul;
                un -= lrate * (mn * inv1) / (sqrtf(vn * inv2) + eps);
                U[j][t] = un; Mo[j][t] = mn; Vo[j][t] = vn;
                const float an = fmaxf(un - 0.25f, 0.0f);
                const int su = (col >> 3) ^ (row & 7);
                act[row * 1024 + (su << 3) + (col & 7)] = (bf16_t)an;
                if (step == 50) {
                    actsf[(size_t)(m0 + row) * 1024 + col] = an;
                    actbf[(size_t)(m0 + row) * 1024 + col] = (bf16_t)an;
                }
            }
        __syncthreads();   // act ready for next step
    }
}

extern "C" void kernel_launch(void* const* d_in, const int* in_sizes, int n_in,
                              void* d_out, int out_size, void* d_ws, size_t ws_size,
                              hipStream_t stream)
{
    const float* images  = (const float*)d_in[0];   // [4096, 4096] (B x P)
    const float* filters = (const float*)d_in[1];   // [4096, 1024] (P x F)
    float* out = (float*)d_out;

    constexpr int B = 4096, P = 4096, F = 1024;
    constexpr size_t BF = (size_t)B * F;   // 4M elems
    constexpr size_t BP = (size_t)B * P;   // 16M elems

    // d_out (80 MB) time-shared:
    //   out[0 : 8M floats)   : xbf (16M bf16)          -> recon overwrites later
    //   out[8M : 12M floats) : excite fp32             -> recon overwrites later
    //   out[16M : 20M floats): acts output (persistent kernel writes it)
    bf16_t* xbf    = (bf16_t*)out;
    float*  excite = out + 2 * BF;
    float*  actsf  = out + BP;

    // d_ws (18 MB): w0 = phiT (8 MB) then actbf ; Gblk (2 MB) ; phibf (8 MB)
    bf16_t* w0    = (bf16_t*)d_ws;
    bf16_t* Gblk  = w0 + BF;               // +8 MB
    bf16_t* phibf = w0 + BF + BF / 4;      // +10 MB

    dim3 blk(256);
    // 1. x -> bf16
    cvt_bf16<<<(unsigned)(BP / 4 / 256), blk, 0, stream>>>(images, xbf, (long)BP);
    // 2. PhiT bf16 [F,P]
    transpose_cvt<<<dim3(F / 32, P / 32), dim3(32, 8), 0, stream>>>(filters, w0);
    // 3. excite = x @ Phi  (A=xbf [B,P], BT=phiT [F,P]) -> fp32 [B,F]
    gemm_bt<0><<<dim3(F / 128, B / 128), blk, 0, stream>>>(
        xbf, w0, B, F, P, excite, nullptr);
    // 4. G = PhiT @ Phi -> blocked bf16 Gblk[k/32][n][k%32]
    gemm_bt<3><<<dim3(F / 128, F / 128), blk, 0, stream>>>(
        w0, w0, F, F, P, nullptr, Gblk);
    // 5. 50 LCA/AdamW steps, persistent. Writes acts fp32 (d_out) + actbf (w0).
    lca_persistent<<<dim3(B / 16), dim3(1024), 0, stream>>>(Gblk, excite, actsf, w0);
    // 6. Phi -> bf16 [P,F]
    cvt_bf16<<<(unsigned)(BF / 4 / 256), blk, 0, stream>>>(filters, phibf, (long)BF);
    // 7. recon = acts @ Phi^T (A=actbf [B,F], BT=phibf [P,F]) -> fp32 [B,P]
    gemm_bt<0><<<dim3(P / 128, B / 128), blk, 0, stream>>>(
        w0, phibf, B, P, F, out, nullptr);
}

// Round 4
// 2127.965 us; speedup vs baseline: 1.0910x; 1.0910x over previous
//
#include <hip/hip_runtime.h>
#include <math.h>

// B=4096 images, P=4096 pixels, F=1024 filters, 50 AdamW steps.
// Round 9 = Round 8 resubmitted (container infra failure, no kernel verdict).
// Theory: reported arch VGPR = 256/waves_per_eu (R5 w=2 -> 128, R6/R7 w=4 ->
// 64) => unified gfx950 file split ~50/50 arch/accum; WRITE_SIZE=1.0GB
// (vs 25MB legit) = ~20 f32/thread/step scratch in the ARCH half while 48
// AGPRs idle. Fix: stash U/M/V (48 f32) in AGPRs via v_accvgpr_read/write
// ("a" constraint), no k-loop unroll (-16 arch), fold Gblk offsets into
// load immediates (-3). AGPR = 48 state + 16 acc = 64; arch ~50 <= 64.
// Math order unchanged -> bit-identical outputs.

typedef __bf16 bf16_t;
typedef __bf16 bf16x8 __attribute__((ext_vector_type(8)));
typedef __bf16 bf16x4 __attribute__((ext_vector_type(4)));
typedef float f32x4 __attribute__((ext_vector_type(4)));

__device__ __forceinline__ void async_ld16(const void* g, void* l) {
    __builtin_amdgcn_global_load_lds(
        (const __attribute__((address_space(1))) void*)g,
        (__attribute__((address_space(3))) void*)l, 16, 0, 0);
}

// AGPR stash: keep long-lived per-thread state in the accumulator half of
// the unified register file (otherwise idle), freeing arch VGPRs.
__device__ __forceinline__ float ag_read(const float& a_) {
    float v;
    asm("v_accvgpr_read_b32 %0, %1" : "=v"(v) : "a"(a_));
    return v;
}
__device__ __forceinline__ void ag_write(float& a_, float v) {
    asm("v_accvgpr_write_b32 %0, %1" : "=a"(a_) : "v"(v));
}

__global__ void cvt_bf16(const float* __restrict__ x, bf16_t* __restrict__ y, long n) {
    long i = ((long)blockIdx.x * blockDim.x + threadIdx.x) * 4;
    if (i + 3 < n) {
        float4 f = *(const float4*)(x + i);
        bf16x4 o = { (bf16_t)f.x, (bf16_t)f.y, (bf16_t)f.z, (bf16_t)f.w };
        *(bf16x4*)(y + i) = o;
    }
}

// PhiT[f][p] = Phi[p][f], fp32 -> bf16.  Phi is [4096,1024].
__global__ void transpose_cvt(const float* __restrict__ src, bf16_t* __restrict__ dst) {
    __shared__ float tile[32][33];
    const int f0 = blockIdx.x * 32;
    const int p0 = blockIdx.y * 32;
    const int tx = threadIdx.x, ty = threadIdx.y;
    for (int r = ty; r < 32; r += 8)
        tile[r][tx] = src[(size_t)(p0 + r) * 1024 + f0 + tx];
    __syncthreads();
    for (int r = ty; r < 32; r += 8)
        dst[(size_t)(f0 + r) * 4096 + p0 + tx] = (bf16_t)tile[tx][r];
}

// C[M,N] = A[M,K] @ BT[N,K]^T (bf16, K-major). 128x128 tile, BK=32.
// MODE 0: store C fp32.  MODE 3: store C bf16 in blocked layout
//   Gblk[row/32][col][row%32]  (requires N==1024).
template<int MODE>
__global__ __launch_bounds__(256) void gemm_bt(
    const bf16_t* __restrict__ A, const bf16_t* __restrict__ BT,
    int M, int N, int K,
    float* __restrict__ Cf, bf16_t* __restrict__ Cb)
{
    __shared__ bf16_t As[128 * 32];
    __shared__ bf16_t Bs[128 * 32];
    const int tid  = threadIdx.x;
    const int n0   = blockIdx.x * 128;
    const int m0   = blockIdx.y * 128;
    const int wave = tid >> 6;
    const int lane = tid & 63;
    const int wm   = (wave >> 1) * 64;
    const int wn   = (wave & 1) * 64;
    const int r0   = tid >> 2;
    const int kc   = (tid & 3) * 8;
    const int lr   = lane >> 4;
    const int lc   = lane & 15;

    f32x4 acc[4][4] = {};
    const size_t arow0 = (size_t)(m0 + r0) * K;
    const size_t arow1 = (size_t)(m0 + 64 + r0) * K;
    const size_t brow0 = (size_t)(n0 + r0) * K;
    const size_t brow1 = (size_t)(n0 + 64 + r0) * K;

    for (int k0 = 0; k0 < K; k0 += 32) {
        async_ld16(A + arow0 + k0 + kc, &As[(size_t)tid * 8]);
        async_ld16(A + arow1 + k0 + kc, &As[(size_t)(tid + 256) * 8]);
        async_ld16(BT + brow0 + k0 + kc, &Bs[(size_t)tid * 8]);
        async_ld16(BT + brow1 + k0 + kc, &Bs[(size_t)(tid + 256) * 8]);
        __syncthreads();
        bf16x8 af[4], bv[4];
#pragma unroll
        for (int i = 0; i < 4; ++i) {
            af[i] = *(const bf16x8*)&As[(wm + i * 16 + lc) * 32 + lr * 8];
            bv[i] = *(const bf16x8*)&Bs[(wn + i * 16 + lc) * 32 + lr * 8];
        }
#pragma unroll
        for (int i = 0; i < 4; ++i)
#pragma unroll
            for (int j = 0; j < 4; ++j)
                acc[i][j] = __builtin_amdgcn_mfma_f32_16x16x32_bf16(af[i], bv[j], acc[i][j], 0, 0, 0);
        __syncthreads();
    }

    // C/D layout: col = lane&15, row = (lane>>4)*4 + reg
#pragma unroll
    for (int i = 0; i < 4; ++i)
#pragma unroll
        for (int t = 0; t < 4; ++t) {
            const int row = m0 + wm + i * 16 + lr * 4 + t;
#pragma unroll
            for (int j = 0; j < 4; ++j) {
                const int col = n0 + wn + j * 16 + lc;
                if constexpr (MODE == 0) {
                    Cf[(size_t)row * N + col] = acc[i][j][t];
                } else {
                    Cb[(size_t)(((row >> 5) << 10) + col) * 32 + (row & 31)] =
                        (bf16_t)acc[i][j][t];
                }
            }
        }
}

// Persistent LCA: each block owns 16 rows for all 50 steps.
// 1024 threads = 16 waves; wave w covers cols [w*64, w*64+64) (4 n-tiles).
// State u,m,v (48 f32/thread) in AGPRs via v_accvgpr stash; acc (16) AGPR;
// excite in LDS fp32 (64 KB); act bf16 in LDS (32 KB, swizzled);
// G read from L2 via blocked layout Gblk[k/32][n][k%32] (coalesced).
// LDS=96KB -> 1 block/CU = 4 waves/EU; arch-VGPR demand ~50 <= 64 cap.
__global__ __launch_bounds__(1024) __attribute__((amdgpu_waves_per_eu(4, 4)))
void lca_persistent(
    const bf16_t* __restrict__ Gblk, const float* __restrict__ excite,
    float* __restrict__ actsf, bf16_t* __restrict__ actbf)
{
    __shared__ bf16_t act[16 * 1024];   // 32 KB, swizzled
    __shared__ float  exs[16 * 1024];   // 64 KB, exs[row][col] == global layout
    const int tid  = threadIdx.x;
    const int m0   = blockIdx.x * 16;
    const int wave = tid >> 6;
    const int lane = tid & 63;
    const int lr   = lane >> 4;
    const int lc   = lane & 15;
    const int wn   = wave * 64;

    // zero act buffer (act_1 = relu(0 - 0.25) = 0)
    for (int i = tid; i < 16 * 1024 / 8; i += 1024) {
        bf16x8 z = {};
        *(bf16x8*)&act[i * 8] = z;
    }
    // stage excite rows [m0, m0+16) into LDS (contiguous copy, 16B/lane)
    {
        const float* esrc = excite + (size_t)m0 * 1024;
        for (int i = tid; i < 16 * 1024 / 4; i += 1024)
            *(f32x4*)&exs[i * 4] = *(const f32x4*)(esrc + (size_t)i * 4);
    }
    __syncthreads();

    // AGPR-resident state (48 f32/thread)
    float Ua[4][4], Ma[4][4], Va[4][4];
#pragma unroll
    for (int j = 0; j < 4; ++j)
#pragma unroll
        for (int t = 0; t < 4; ++t) {
            ag_write(Ua[j][t], 0.0f);
            ag_write(Ma[j][t], 0.0f);
            ag_write(Va[j][t], 0.0f);
        }

    // per-thread invariant offsets
    const int aoff = lc * 1024;       // act row base (elements)
    const int lcx  = lc & 7;
    // Gblk per-thread base: row (wn+lc) of block 0, k-sub lr*8.
    // j-tile offsets are j*512 elems = j*1024 B -> folded into load immediates.
    const bf16_t* gpt = Gblk + (((wn + lc) << 5) + lr * 8);

    const float lrate = 0.1f, b1 = 0.9f, b2 = 0.999f, eps = 1e-8f;
    const float wdmul = 1.0f - lrate * 1e-2f;
    float pb1 = 1.0f, pb2 = 1.0f;

    for (int step = 1; step <= 50; ++step) {
        pb1 *= b1; pb2 *= b2;
        const float inv1 = 1.0f / (1.0f - pb1);
        const float inv2 = 1.0f / (1.0f - pb2);

        f32x4 acc[4] = {};
#pragma unroll 1
        for (int kcb = 0; kcb < 32; ++kcb) {
            // A-fragment: act[m = lc][k = kcb*32 + lr*8 + 0..7], swizzled
            const int unit = kcb * 4 + lr;
            const bf16x8 a = *(const bf16x8*)&act[aoff + ((unit ^ lcx) << 3)];
            const bf16_t* gp = gpt + ((size_t)kcb << 15);
            bf16x8 b0 = *(const bf16x8*)(gp);
            bf16x8 b1v = *(const bf16x8*)(gp + 512);
            bf16x8 b2v = *(const bf16x8*)(gp + 1024);
            bf16x8 b3 = *(const bf16x8*)(gp + 1536);
            acc[0] = __builtin_amdgcn_mfma_f32_16x16x32_bf16(a, b0,  acc[0], 0, 0, 0);
            acc[1] = __builtin_amdgcn_mfma_f32_16x16x32_bf16(a, b1v, acc[1], 0, 0, 0);
            acc[2] = __builtin_amdgcn_mfma_f32_16x16x32_bf16(a, b2v, acc[2], 0, 0, 0);
            acc[3] = __builtin_amdgcn_mfma_f32_16x16x32_bf16(a, b3,  acc[3], 0, 0, 0);
        }
        __syncthreads();   // all waves done reading act

#pragma unroll
        for (int j = 0; j < 4; ++j)
#pragma unroll
            for (int t = 0; t < 4; ++t) {
                const int row = lr * 4 + t;
                const int col = wn + j * 16 + lc;
                const float ex   = exs[row * 1024 + col];
                const float uold = ag_read(Ua[j][t]);
                const float mold = ag_read(Ma[j][t]);
                const float vold = ag_read(Va[j][t]);
                const float aold = fmaxf(uold - 0.25f, 0.0f);
                const float g    = uold - ex + acc[j][t] - aold;
                const float mn   = b1 * mold + (1.0f - b1) * g;
                const float vn   = b2 * vold + (1.0f - b2) * g * g;
                float un = uold * wdmul;
                un -= lrate * (mn * inv1) / (sqrtf(vn * inv2) + eps);
                ag_write(Ua[j][t], un);
                ag_write(Ma[j][t], mn);
                ag_write(Va[j][t], vn);
                const float an = fmaxf(un - 0.25f, 0.0f);
                const int su = (col >> 3) ^ (row & 7);
                act[row * 1024 + (su << 3) + (col & 7)] = (bf16_t)an;
                if (step == 50) {
                    actsf[(size_t)(m0 + row) * 1024 + col] = an;
                    actbf[(size_t)(m0 + row) * 1024 + col] = (bf16_t)an;
                }
            }
        __syncthreads();   // act ready for next step
    }
}

extern "C" void kernel_launch(void* const* d_in, const int* in_sizes, int n_in,
                              void* d_out, int out_size, void* d_ws, size_t ws_size,
                              hipStream_t stream)
{
    const float* images  = (const float*)d_in[0];   // [4096, 4096] (B x P)
    const float* filters = (const float*)d_in[1];   // [4096, 1024] (P x F)
    float* out = (float*)d_out;

    constexpr int B = 4096, P = 4096, F = 1024;
    constexpr size_t BF = (size_t)B * F;   // 4M elems
    constexpr size_t BP = (size_t)B * P;   // 16M elems

    // d_out (80 MB) time-shared:
    //   out[0 : 8M floats)   : xbf (16M bf16)          -> recon overwrites later
    //   out[8M : 12M floats) : excite fp32             -> recon overwrites later
    //   out[16M : 20M floats): acts output (persistent kernel writes it)
    bf16_t* xbf    = (bf16_t*)out;
    float*  excite = out + 2 * BF;
    float*  actsf  = out + BP;

    // d_ws (18 MB): w0 = phiT (8 MB) then actbf ; Gblk (2 MB) ; phibf (8 MB)
    bf16_t* w0    = (bf16_t*)d_ws;
    bf16_t* Gblk  = w0 + BF;               // +8 MB
    bf16_t* phibf = w0 + BF + BF / 4;      // +10 MB

    dim3 blk(256);
    // 1. x -> bf16
    cvt_bf16<<<(unsigned)(BP / 4 / 256), blk, 0, stream>>>(images, xbf, (long)BP);
    // 2. PhiT bf16 [F,P]
    transpose_cvt<<<dim3(F / 32, P / 32), dim3(32, 8), 0, stream>>>(filters, w0);
    // 3. excite = x @ Phi  (A=xbf [B,P], BT=phiT [F,P]) -> fp32 [B,F]
    gemm_bt<0><<<dim3(F / 128, B / 128), blk, 0, stream>>>(
        xbf, w0, B, F, P, excite, nullptr);
    // 4. G = PhiT @ Phi -> blocked bf16 Gblk[k/32][n][k%32]
    gemm_bt<3><<<dim3(F / 128, F / 128), blk, 0, stream>>>(
        w0, w0, F, F, P, nullptr, Gblk);
    // 5. 50 LCA/AdamW steps, persistent. Writes acts fp32 (d_out) + actbf (w0).
    lca_persistent<<<dim3(B / 16), dim3(1024), 0, stream>>>(Gblk, excite, actsf, w0);
    // 6. Phi -> bf16 [P,F]
    cvt_bf16<<<(unsigned)(BF / 4 / 256), blk, 0, stream>>>(filters, phibf, (long)BF);
    // 7. recon = acts @ Phi^T (A=actbf [B,F], BT=phibf [P,F]) -> fp32 [B,P]
    gemm_bt<0><<<dim3(P / 128, B / 128), blk, 0, stream>>>(
        w0, phibf, B, P, F, out, nullptr);
}

// Round 5
// 2105.082 us; speedup vs baseline: 1.1029x; 1.0109x over previous
//
#include <hip/hip_runtime.h>
#include <math.h>

// B=4096 images, P=4096 pixels, F=1024 filters, 50 AdamW steps.
// Round 10: latency attack. R9 killed the spill (WRITE 1.0GB->59MB, AGPR
// stash works) but dur only -10%: kernel is latency-bound (L2-eff 13.7 of
// 34.5 TB/s, nothing saturated) because the unrolled pipeline was removed.
// Floor: each CU streams 2MB Gblk/step from L2 at ~56B/cy -> ~780us/50 steps.
// Fixes: (1) half-pipelined k-loop (pair A of kcb+1 + next a-frag prefetched
// while pair B of kcb runs MFMA; live b=32 regs -> fits 64-arch cap),
// (2) exs -> per-thread f32x4 fragment layout (conflict-free b128 reads;
// old row-major had 4-way conflicts since 1024 % 32 == 0),
// (3) step-50 stores hoisted out of the loop. Math order unchanged.

typedef __bf16 bf16_t;
typedef __bf16 bf16x8 __attribute__((ext_vector_type(8)));
typedef __bf16 bf16x4 __attribute__((ext_vector_type(4)));
typedef float f32x4 __attribute__((ext_vector_type(4)));

__device__ __forceinline__ void async_ld16(const void* g, void* l) {
    __builtin_amdgcn_global_load_lds(
        (const __attribute__((address_space(1))) void*)g,
        (__attribute__((address_space(3))) void*)l, 16, 0, 0);
}

// AGPR stash: long-lived per-thread state in the accumulator half of the
// unified register file (arch half is capped at 64 regs at 4 waves/EU).
__device__ __forceinline__ float ag_read(const float& a_) {
    float v;
    asm("v_accvgpr_read_b32 %0, %1" : "=v"(v) : "a"(a_));
    return v;
}
__device__ __forceinline__ void ag_write(float& a_, float v) {
    asm("v_accvgpr_write_b32 %0, %1" : "=a"(a_) : "v"(v));
}

__global__ void cvt_bf16(const float* __restrict__ x, bf16_t* __restrict__ y, long n) {
    long i = ((long)blockIdx.x * blockDim.x + threadIdx.x) * 4;
    if (i + 3 < n) {
        float4 f = *(const float4*)(x + i);
        bf16x4 o = { (bf16_t)f.x, (bf16_t)f.y, (bf16_t)f.z, (bf16_t)f.w };
        *(bf16x4*)(y + i) = o;
    }
}

// PhiT[f][p] = Phi[p][f], fp32 -> bf16.  Phi is [4096,1024].
__global__ void transpose_cvt(const float* __restrict__ src, bf16_t* __restrict__ dst) {
    __shared__ float tile[32][33];
    const int f0 = blockIdx.x * 32;
    const int p0 = blockIdx.y * 32;
    const int tx = threadIdx.x, ty = threadIdx.y;
    for (int r = ty; r < 32; r += 8)
        tile[r][tx] = src[(size_t)(p0 + r) * 1024 + f0 + tx];
    __syncthreads();
    for (int r = ty; r < 32; r += 8)
        dst[(size_t)(f0 + r) * 4096 + p0 + tx] = (bf16_t)tile[tx][r];
}

// C[M,N] = A[M,K] @ BT[N,K]^T (bf16, K-major). 128x128 tile, BK=32.
// MODE 0: store C fp32.  MODE 3: store C bf16 in blocked layout
//   Gblk[row/32][col][row%32]  (requires N==1024).
template<int MODE>
__global__ __launch_bounds__(256) void gemm_bt(
    const bf16_t* __restrict__ A, const bf16_t* __restrict__ BT,
    int M, int N, int K,
    float* __restrict__ Cf, bf16_t* __restrict__ Cb)
{
    __shared__ bf16_t As[128 * 32];
    __shared__ bf16_t Bs[128 * 32];
    const int tid  = threadIdx.x;
    const int n0   = blockIdx.x * 128;
    const int m0   = blockIdx.y * 128;
    const int wave = tid >> 6;
    const int lane = tid & 63;
    const int wm   = (wave >> 1) * 64;
    const int wn   = (wave & 1) * 64;
    const int r0   = tid >> 2;
    const int kc   = (tid & 3) * 8;
    const int lr   = lane >> 4;
    const int lc   = lane & 15;

    f32x4 acc[4][4] = {};
    const size_t arow0 = (size_t)(m0 + r0) * K;
    const size_t arow1 = (size_t)(m0 + 64 + r0) * K;
    const size_t brow0 = (size_t)(n0 + r0) * K;
    const size_t brow1 = (size_t)(n0 + 64 + r0) * K;

    for (int k0 = 0; k0 < K; k0 += 32) {
        async_ld16(A + arow0 + k0 + kc, &As[(size_t)tid * 8]);
        async_ld16(A + arow1 + k0 + kc, &As[(size_t)(tid + 256) * 8]);
        async_ld16(BT + brow0 + k0 + kc, &Bs[(size_t)tid * 8]);
        async_ld16(BT + brow1 + k0 + kc, &Bs[(size_t)(tid + 256) * 8]);
        __syncthreads();
        bf16x8 af[4], bv[4];
#pragma unroll
        for (int i = 0; i < 4; ++i) {
            af[i] = *(const bf16x8*)&As[(wm + i * 16 + lc) * 32 + lr * 8];
            bv[i] = *(const bf16x8*)&Bs[(wn + i * 16 + lc) * 32 + lr * 8];
        }
#pragma unroll
        for (int i = 0; i < 4; ++i)
#pragma unroll
            for (int j = 0; j < 4; ++j)
                acc[i][j] = __builtin_amdgcn_mfma_f32_16x16x32_bf16(af[i], bv[j], acc[i][j], 0, 0, 0);
        __syncthreads();
    }

    // C/D layout: col = lane&15, row = (lane>>4)*4 + reg
#pragma unroll
    for (int i = 0; i < 4; ++i)
#pragma unroll
        for (int t = 0; t < 4; ++t) {
            const int row = m0 + wm + i * 16 + lr * 4 + t;
#pragma unroll
            for (int j = 0; j < 4; ++j) {
                const int col = n0 + wn + j * 16 + lc;
                if constexpr (MODE == 0) {
                    Cf[(size_t)row * N + col] = acc[i][j][t];
                } else {
                    Cb[(size_t)(((row >> 5) << 10) + col) * 32 + (row & 31)] =
                        (bf16_t)acc[i][j][t];
                }
            }
        }
}

// Persistent LCA: each block owns 16 rows for all 50 steps.
// 1024 threads = 16 waves; wave w covers cols [w*64, w*64+64) (4 n-tiles).
// State u,m,v (48 f32/thread) + acc (16) in AGPRs (64 = full accum half);
// excite in LDS as per-thread f32x4 fragments (64 KB, conflict-free);
// act bf16 in LDS (32 KB, swizzled); G streamed from L2 via blocked layout
// Gblk[k/32][n][k%32], half-pipelined (pair-ahead prefetch, ~60 arch regs).
__global__ __launch_bounds__(1024) __attribute__((amdgpu_waves_per_eu(4, 4)))
void lca_persistent(
    const bf16_t* __restrict__ Gblk, const float* __restrict__ excite,
    float* __restrict__ actsf, bf16_t* __restrict__ actbf)
{
    __shared__ bf16_t act[16 * 1024];   // 32 KB, swizzled
    __shared__ f32x4  exsv[4096];       // 64 KB, exsv[j*1024 + tid]
    const int tid  = threadIdx.x;
    const int m0   = blockIdx.x * 16;
    const int wave = tid >> 6;
    const int lane = tid & 63;
    const int lr   = lane >> 4;
    const int lc   = lane & 15;
    const int wn   = wave * 64;

    // zero act buffer (act_1 = relu(0 - 0.25) = 0)
    for (int i = tid; i < 16 * 1024 / 8; i += 1024) {
        bf16x8 z = {};
        *(bf16x8*)&act[i * 8] = z;
    }
    // stage excite into per-thread fragment layout (one-time gather)
#pragma unroll
    for (int j = 0; j < 4; ++j) {
        f32x4 e;
#pragma unroll
        for (int t = 0; t < 4; ++t)
            e[t] = excite[(size_t)(m0 + lr * 4 + t) * 1024 + wn + j * 16 + lc];
        exsv[j * 1024 + tid] = e;
    }
    __syncthreads();

    // AGPR-resident state (48 f32/thread)
    float Ua[4][4], Ma[4][4], Va[4][4];
#pragma unroll
    for (int j = 0; j < 4; ++j)
#pragma unroll
        for (int t = 0; t < 4; ++t) {
            ag_write(Ua[j][t], 0.0f);
            ag_write(Ma[j][t], 0.0f);
            ag_write(Va[j][t], 0.0f);
        }

    // per-thread invariant offsets
    const int aoff = lc * 1024;       // act row base (elements)
    const int lcx  = lc & 7;
    const bf16_t* gpt = Gblk + (((wn + lc) << 5) + lr * 8);

    const float lrate = 0.1f, b1 = 0.9f, b2 = 0.999f, eps = 1e-8f;
    const float wdmul = 1.0f - lrate * 1e-2f;
    float pb1 = 1.0f, pb2 = 1.0f;

    for (int step = 1; step <= 50; ++step) {
        pb1 *= b1; pb2 *= b2;
        const float inv1 = 1.0f / (1.0f - pb1);
        const float inv2 = 1.0f / (1.0f - pb2);

        f32x4 acc[4] = {};
        {
            // half-pipelined k-loop: pair A (j=0,1) of kcb+1 and next
            // a-fragment are issued while pair B (j=2,3) of kcb is MFMA'd.
            const bf16_t* gp = gpt;
            bf16x8 a_cur = *(const bf16x8*)&act[aoff + ((lr ^ lcx) << 3)];
            bf16x8 p0 = *(const bf16x8*)(gp);
            bf16x8 p1 = *(const bf16x8*)(gp + 512);
            bf16x8 a_nxt, n0, n1;
#pragma unroll 1
            for (int kcb = 0; kcb < 32; ++kcb) {
                bf16x8 q0 = *(const bf16x8*)(gp + 1024);
                bf16x8 q1 = *(const bf16x8*)(gp + 1536);
                acc[0] = __builtin_amdgcn_mfma_f32_16x16x32_bf16(a_cur, p0, acc[0], 0, 0, 0);
                acc[1] = __builtin_amdgcn_mfma_f32_16x16x32_bf16(a_cur, p1, acc[1], 0, 0, 0);
                if (kcb < 31) {
                    const int unit = (kcb + 1) * 4 + lr;
                    a_nxt = *(const bf16x8*)&act[aoff + ((unit ^ lcx) << 3)];
                    gp += (size_t)1 << 15;
                    n0 = *(const bf16x8*)(gp);
                    n1 = *(const bf16x8*)(gp + 512);
                }
                acc[2] = __builtin_amdgcn_mfma_f32_16x16x32_bf16(a_cur, q0, acc[2], 0, 0, 0);
                acc[3] = __builtin_amdgcn_mfma_f32_16x16x32_bf16(a_cur, q1, acc[3], 0, 0, 0);
                a_cur = a_nxt; p0 = n0; p1 = n1;
            }
        }
        __syncthreads();   // all waves done reading act

#pragma unroll
        for (int j = 0; j < 4; ++j) {
            const f32x4 ex4 = exsv[j * 1024 + tid];
#pragma unroll
            for (int t = 0; t < 4; ++t) {
                const int row = lr * 4 + t;
                const int col = wn + j * 16 + lc;
                const float uold = ag_read(Ua[j][t]);
                const float mold = ag_read(Ma[j][t]);
                const float vold = ag_read(Va[j][t]);
                const float aold = fmaxf(uold - 0.25f, 0.0f);
                const float g    = uold - ex4[t] + acc[j][t] - aold;
                const float mn   = b1 * mold + (1.0f - b1) * g;
                const float vn   = b2 * vold + (1.0f - b2) * g * g;
                float un = uold * wdmul;
                un -= lrate * (mn * inv1) / (sqrtf(vn * inv2) + eps);
                ag_write(Ua[j][t], un);
                ag_write(Ma[j][t], mn);
                ag_write(Va[j][t], vn);
                const float an = fmaxf(un - 0.25f, 0.0f);
                const int su = (col >> 3) ^ (row & 7);
                act[row * 1024 + (su << 3) + (col & 7)] = (bf16_t)an;
            }
        }
        __syncthreads();   // act ready for next step
    }

    // final outputs: act_50 = relu(u_50 - 0.25), recomputed from AGPR state
#pragma unroll
    for (int j = 0; j < 4; ++j)
#pragma unroll
        for (int t = 0; t < 4; ++t) {
            const int row = lr * 4 + t;
            const int col = wn + j * 16 + lc;
            const float an = fmaxf(ag_read(Ua[j][t]) - 0.25f, 0.0f);
            actsf[(size_t)(m0 + row) * 1024 + col] = an;
            actbf[(size_t)(m0 + row) * 1024 + col] = (bf16_t)an;
        }
}

extern "C" void kernel_launch(void* const* d_in, const int* in_sizes, int n_in,
                              void* d_out, int out_size, void* d_ws, size_t ws_size,
                              hipStream_t stream)
{
    const float* images  = (const float*)d_in[0];   // [4096, 4096] (B x P)
    const float* filters = (const float*)d_in[1];   // [4096, 1024] (P x F)
    float* out = (float*)d_out;

    constexpr int B = 4096, P = 4096, F = 1024;
    constexpr size_t BF = (size_t)B * F;   // 4M elems
    constexpr size_t BP = (size_t)B * P;   // 16M elems

    // d_out (80 MB) time-shared:
    //   out[0 : 8M floats)   : xbf (16M bf16)          -> recon overwrites later
    //   out[8M : 12M floats) : excite fp32             -> recon overwrites later
    //   out[16M : 20M floats): acts output (persistent kernel writes it)
    bf16_t* xbf    = (bf16_t*)out;
    float*  excite = out + 2 * BF;
    float*  actsf  = out + BP;

    // d_ws (18 MB): w0 = phiT (8 MB) then actbf ; Gblk (2 MB) ; phibf (8 MB)
    bf16_t* w0    = (bf16_t*)d_ws;
    bf16_t* Gblk  = w0 + BF;               // +8 MB
    bf16_t* phibf = w0 + BF + BF / 4;      // +10 MB

    dim3 blk(256);
    // 1. x -> bf16
    cvt_bf16<<<(unsigned)(BP / 4 / 256), blk, 0, stream>>>(images, xbf, (long)BP);
    // 2. PhiT bf16 [F,P]
    transpose_cvt<<<dim3(F / 32, P / 32), dim3(32, 8), 0, stream>>>(filters, w0);
    // 3. excite = x @ Phi  (A=xbf [B,P], BT=phiT [F,P]) -> fp32 [B,F]
    gemm_bt<0><<<dim3(F / 128, B / 128), blk, 0, stream>>>(
        xbf, w0, B, F, P, excite, nullptr);
    // 4. G = PhiT @ Phi -> blocked bf16 Gblk[k/32][n][k%32]
    gemm_bt<3><<<dim3(F / 128, F / 128), blk, 0, stream>>>(
        w0, w0, F, F, P, nullptr, Gblk);
    // 5. 50 LCA/AdamW steps, persistent. Writes acts fp32 (d_out) + actbf (w0).
    lca_persistent<<<dim3(B / 16), dim3(1024), 0, stream>>>(Gblk, excite, actsf, w0);
    // 6. Phi -> bf16 [P,F]
    cvt_bf16<<<(unsigned)(BF / 4 / 256), blk, 0, stream>>>(filters, phibf, (long)BF);
    // 7. recon = acts @ Phi^T (A=actbf [B,F], BT=phibf [P,F]) -> fp32 [B,P]
    gemm_bt<0><<<dim3(P / 128, B / 128), blk, 0, stream>>>(
        w0, phibf, B, P, F, out, nullptr);
}